// Round 3
// baseline (753.938 us; speedup 1.0000x reference)
//
#include <hip/hip_runtime.h>
#include <stdint.h>

// Problem constants (B=2, S=2048 -> T=4096 tokens)
#define T_TOK 4096
#define Dm    1024
#define Em    8
#define Hm    4096
#define NSLOT (2 * T_TOK)   // 8192 (token,expert) slots
#define KSPLIT 2            // gemm2 split-K factor

typedef __bf16 bf16x8 __attribute__((ext_vector_type(8)));
typedef float  f32x4  __attribute__((ext_vector_type(4)));
typedef unsigned short us8v __attribute__((ext_vector_type(8)));

__device__ __forceinline__ unsigned short f2bf(float f) {
  union { float f; unsigned int u; } c; c.f = f;
  unsigned int u = c.u;
  unsigned int r = u + 0x7fffu + ((u >> 16) & 1u);  // round-to-nearest-even
  return (unsigned short)(r >> 16);
}

// async 16B/lane global->LDS copy (wave-uniform LDS base + lane*16)
__device__ __forceinline__ void async16(const void* g, void* l) {
  __builtin_amdgcn_global_load_lds(
      (const __attribute__((address_space(1))) void*)g,
      (__attribute__((address_space(3))) void*)l, 16, 0, 0);
}

// ---------------- transpose + fp32->bf16 convert (128R x 32C tiles) ----------------
// src: [E][R][C] fp32, dst: [E][C][R] bf16.  grid (C/32, R/128, E), block 256.
// Loads: float4, fully coalesced. LDS stride 33 (33 % 32 == 1 -> near-conflict-free
// column reads). Stores: ushort8 (16B); 16 lanes cover 256B contiguous per out-row.
__global__ __launch_bounds__(256) void transpose_cvt_kernel(
    const float* __restrict__ src, unsigned short* __restrict__ dst, int R, int C) {
  __shared__ float tile[128][33];
  const int e = blockIdx.z;
  const float* s = src + (size_t)e * R * C;
  unsigned short* d = dst + (size_t)e * R * C;
  const int c0 = blockIdx.x * 32, r0 = blockIdx.y * 128;
  const int tid = threadIdx.x;

  // load: 32 rows per pass x 32 cols (8 lanes * float4 per row), 4 passes
  const int lrow = tid >> 3, lc = (tid & 7) * 4;
#pragma unroll
  for (int p = 0; p < 4; ++p) {
    const int row = lrow + p * 32;
    float4 v = *(const float4*)(s + (size_t)(r0 + row) * C + c0 + lc);
    tile[row][lc + 0] = v.x; tile[row][lc + 1] = v.y;
    tile[row][lc + 2] = v.z; tile[row][lc + 3] = v.w;
  }
  __syncthreads();

  // store: out-row c covers 128 r values; lane takes 8 consecutive r (ushort8)
  const int rb = (tid & 15) * 8;
#pragma unroll
  for (int p = 0; p < 2; ++p) {
    const int c = (tid >> 4) + p * 16;
    us8v o;
#pragma unroll
    for (int k = 0; k < 8; ++k) o[k] = f2bf(tile[rb + k][c]);
    *(us8v*)(d + (size_t)(c0 + c) * R + r0 + rb) = o;
  }
}

// ---------------- router: one wave per token (also emits xbf = bf16(x)) ----------------
__global__ __launch_bounds__(256) void router_kernel(
    const float* __restrict__ x, const float* __restrict__ noise,
    const float* __restrict__ Wr, const float* __restrict__ br,
    const float* __restrict__ Wn, const float* __restrict__ bn,
    float* __restrict__ out_gating, int* __restrict__ lists,
    int* __restrict__ counts, float* __restrict__ gslot,
    unsigned short* __restrict__ xbf) {
  const int wave = threadIdx.x >> 6, lane = threadIdx.x & 63;
  const int t = blockIdx.x * 4 + wave;
  const float* xt = x + (size_t)t * Dm;
  float accR[Em] = {}, accN[Em] = {};
  for (int d = lane; d < Dm; d += 64) {
    const float xv = xt[d];
    xbf[(size_t)t * Dm + d] = f2bf(xv);       // fused x -> bf16 cast
    const float* wr = Wr + d * Em;
    const float* wn = Wn + d * Em;
#pragma unroll
    for (int e = 0; e < Em; e++) { accR[e] += xv * wr[e]; accN[e] += xv * wn[e]; }
  }
#pragma unroll
  for (int e = 0; e < Em; e++)
    for (int off = 32; off > 0; off >>= 1) {
      accR[e] += __shfl_down(accR[e], off, 64);
      accN[e] += __shfl_down(accN[e], off, 64);
    }
  if (lane == 0) {
    float lg[Em], ny[Em];
#pragma unroll
    for (int e = 0; e < Em; e++) {
      lg[e] = accR[e] + br[e];
      float nl = accN[e] + bn[e];
      float sp = fmaxf(nl, 0.f) + log1pf(expf(-fabsf(nl)));  // stable softplus
      ny[e] = lg[e] + noise[(size_t)t * Em + e] * sp;
    }
    // top-2, first-occurrence tie-break (matches lax.top_k)
    int i0 = 0;
#pragma unroll
    for (int e = 1; e < Em; e++) if (ny[e] > ny[i0]) i0 = e;
    int i1 = (i0 == 0) ? 1 : 0;
#pragma unroll
    for (int e = 0; e < Em; e++) if (e != i0 && ny[e] > ny[i1]) i1 = e;
    const float e1 = expf(ny[i1] - ny[i0]);
    const float g0 = 1.f / (1.f + e1), g1 = e1 / (1.f + e1);
    // dense softmax of clean logits (output 2)
    float m = lg[0];
#pragma unroll
    for (int e = 1; e < Em; e++) m = fmaxf(m, lg[e]);
    float s = 0.f;
#pragma unroll
    for (int e = 0; e < Em; e++) s += expf(lg[e] - m);
#pragma unroll
    for (int e = 0; e < Em; e++) out_gating[(size_t)t * Em + e] = expf(lg[e] - m) / s;
    // append to expert lists + per-slot gate
    int p0 = atomicAdd(&counts[i0], 1); lists[i0 * T_TOK + p0] = t;
    int p1 = atomicAdd(&counts[i1], 1); lists[i1 * T_TOK + p1] = t;
    gslot[i0 * T_TOK + p0] = g0;
    gslot[i1 * T_TOK + p1] = g1;
  }
}

// ---------------- GEMM1: hbuf[base+m][h] = relu(Xg[m] . W1t[h] + b1) ----------------
// 3-deep LDS pipeline, prefetch distance 2, counted vmcnt + raw s_barrier.
// grid (E, 16 m-tiles, 32 n-tiles): expert = blockIdx.x = linear_id % 8 -> one XCD.
__global__ __launch_bounds__(256) void gemm1_kernel(
    const unsigned short* __restrict__ xbf, const unsigned short* __restrict__ w1bf,
    const float* __restrict__ b1, const int* __restrict__ counts,
    const int* __restrict__ lists, unsigned short* __restrict__ hbuf) {
  const int e = blockIdx.x;
  const int cnt = counts[e];
  const int m0 = blockIdx.y * 128;
  if (m0 >= cnt) return;
  const int n0 = blockIdx.z * 128;
  int base = 0;
  for (int i = 0; i < e; i++) base += counts[i];

  __shared__ __align__(16) unsigned short As[3][128 * 32];
  __shared__ __align__(16) unsigned short Bs[3][128 * 32];
  __shared__ int tok[128];

  const int tid = threadIdx.x;
  if (tid < 128) {
    int m = m0 + tid;
    tok[tid] = (m < cnt) ? lists[e * T_TOK + m] : 0;
  }
  __syncthreads();   // also drains vmcnt -> clean baseline for counted waits

  const int part = tid & 3;          // 16B chunk within 64B row
  const int r0 = tid >> 2;           // rows 0..63
  const int r1 = r0 + 64;
  const size_t gA0 = (size_t)tok[r0] * Dm + part * 8;
  const size_t gA1 = (size_t)tok[r1] * Dm + part * 8;
  const size_t gB0 = ((size_t)e * Hm + n0 + r0) * Dm + part * 8;
  const size_t gB1 = ((size_t)e * Hm + n0 + r1) * Dm + part * 8;

  const int lane = tid & 63, wv = tid >> 6;
  const int quad = lane >> 4, l15 = lane & 15;
  const int wm = (wv >> 1) * 64, wn = (wv & 1) * 64;
  const int lds_off = wv * 512;      // wave-uniform base (lane*16B implicit)

  f32x4 acc[4][4] = {};

  // prologue: tiles 0 and 1 in flight (8 loads/wave)
  async16(xbf + gA0,       As[0] + lds_off);
  async16(xbf + gA1,       As[0] + 2048 + lds_off);
  async16(w1bf + gB0,      Bs[0] + lds_off);
  async16(w1bf + gB1,      Bs[0] + 2048 + lds_off);
  async16(xbf + gA0 + 32,  As[1] + lds_off);
  async16(xbf + gA1 + 32,  As[1] + 2048 + lds_off);
  async16(w1bf + gB0 + 32, Bs[1] + lds_off);
  async16(w1bf + gB1 + 32, Bs[1] + 2048 + lds_off);

  const int NI = Dm / 32;  // 32
  int cur = 0;
  for (int it = 0; it < NI; ++it) {
    if (it < NI - 1) {
      asm volatile("s_waitcnt vmcnt(4)" ::: "memory");
    } else {
      asm volatile("s_waitcnt vmcnt(0)" ::: "memory");
    }
    __builtin_amdgcn_s_barrier();          // all waves' tile-it data now in LDS
    __builtin_amdgcn_sched_barrier(0);     // pin: no ds_read hoists above barrier
    if (it + 2 < NI) {
      const int k0 = (it + 2) * 32;
      int nb = cur + 2; if (nb >= 3) nb -= 3;   // buffer read 2 iters ago: reads retired
      async16(xbf + gA0 + k0, As[nb] + lds_off);
      async16(xbf + gA1 + k0, As[nb] + 2048 + lds_off);
      async16(w1bf + gB0 + k0, Bs[nb] + lds_off);
      async16(w1bf + gB1 + k0, Bs[nb] + 2048 + lds_off);
    }
    bf16x8 af[4], bfv[4];
#pragma unroll
    for (int i = 0; i < 4; i++)
      af[i] = *(const bf16x8*)(As[cur] + (wm + i * 16 + l15) * 32 + quad * 8);
#pragma unroll
    for (int j = 0; j < 4; j++)
      bfv[j] = *(const bf16x8*)(Bs[cur] + (wn + j * 16 + l15) * 32 + quad * 8);
#pragma unroll
    for (int i = 0; i < 4; i++)
#pragma unroll
      for (int j = 0; j < 4; j++)
        acc[i][j] = __builtin_amdgcn_mfma_f32_16x16x32_bf16(af[i], bfv[j], acc[i][j], 0, 0, 0);
    cur = (cur == 2) ? 0 : cur + 1;
  }

#pragma unroll
  for (int i = 0; i < 4; i++)
#pragma unroll
    for (int r = 0; r < 4; r++) {
      const int ml = wm + i * 16 + quad * 4 + r;   // C/D row = quad*4+reg
      const int m = m0 + ml;
      if (m < cnt) {
#pragma unroll
        for (int j = 0; j < 4; j++) {
          const int n = n0 + wn + j * 16 + l15;    // C/D col = lane&15
          float v = acc[i][j][r] + b1[(size_t)e * Hm + n];
          v = fmaxf(v, 0.f);
          hbuf[(size_t)(base + m) * Hm + n] = f2bf(v);
        }
      }
    }
}

// ---------------- GEMM2 (split-K) + fused gated combine ----------------
// out[t][n] += g_slot * (H[slot] . W2t[n] over K-half  + (ks==0 ? b2[e][n] : 0))
// same 3-deep counted-vmcnt pipeline; epilogue = fp32 atomicAdd scatter.
__global__ __launch_bounds__(256) void gemm2_kernel(
    const unsigned short* __restrict__ hbuf, const unsigned short* __restrict__ w2bf,
    const int* __restrict__ counts, const int* __restrict__ lists,
    const float* __restrict__ gslot, const float* __restrict__ b2,
    float* __restrict__ out) {
  const int e = blockIdx.x;
  const int ks = blockIdx.z & 1;
  const int cnt = counts[e];
  const int m0 = blockIdx.y * 128;
  if (m0 >= cnt) return;
  const int n0 = (blockIdx.z >> 1) * 128;   // N = 1024
  int base = 0;
  for (int i = 0; i < e; i++) base += counts[i];
  const int kbase = ks * (Hm / KSPLIT);  // 0 or 2048

  __shared__ __align__(16) unsigned short As[3][128 * 32];
  __shared__ __align__(16) unsigned short Bs[3][128 * 32];
  __shared__ int tok[128];
  __shared__ float gt[128];

  const int tid = threadIdx.x;
  if (tid < 128) {
    int m = m0 + tid;
    tok[tid] = (m < cnt) ? lists[e * T_TOK + m] : 0;
    gt[tid]  = (m < cnt) ? gslot[e * T_TOK + m] : 0.f;
  }
  __syncthreads();

  const int part = tid & 3;
  const int r0 = tid >> 2;
  const int r1 = r0 + 64;
  const int rowA0 = min(base + m0 + r0, NSLOT - 1);  // clamp: tail rows read junk, unused
  const int rowA1 = min(base + m0 + r1, NSLOT - 1);
  const size_t gA0 = (size_t)rowA0 * Hm + kbase + part * 8;
  const size_t gA1 = (size_t)rowA1 * Hm + kbase + part * 8;
  const size_t gB0 = ((size_t)e * Dm + n0 + r0) * Hm + kbase + part * 8;
  const size_t gB1 = ((size_t)e * Dm + n0 + r1) * Hm + kbase + part * 8;

  const int lane = tid & 63, wv = tid >> 6;
  const int quad = lane >> 4, l15 = lane & 15;
  const int wm = (wv >> 1) * 64, wn = (wv & 1) * 64;
  const int lds_off = wv * 512;

  f32x4 acc[4][4] = {};

  async16(hbuf + gA0,       As[0] + lds_off);
  async16(hbuf + gA1,       As[0] + 2048 + lds_off);
  async16(w2bf + gB0,       Bs[0] + lds_off);
  async16(w2bf + gB1,       Bs[0] + 2048 + lds_off);
  async16(hbuf + gA0 + 32,  As[1] + lds_off);
  async16(hbuf + gA1 + 32,  As[1] + 2048 + lds_off);
  async16(w2bf + gB0 + 32,  Bs[1] + lds_off);
  async16(w2bf + gB1 + 32,  Bs[1] + 2048 + lds_off);

  const int NI = Hm / KSPLIT / 32;  // 64
  int cur = 0;
  for (int it = 0; it < NI; ++it) {
    if (it < NI - 1) {
      asm volatile("s_waitcnt vmcnt(4)" ::: "memory");
    } else {
      asm volatile("s_waitcnt vmcnt(0)" ::: "memory");
    }
    __builtin_amdgcn_s_barrier();
    __builtin_amdgcn_sched_barrier(0);
    if (it + 2 < NI) {
      const int k0 = (it + 2) * 32;
      int nb = cur + 2; if (nb >= 3) nb -= 3;
      async16(hbuf + gA0 + k0, As[nb] + lds_off);
      async16(hbuf + gA1 + k0, As[nb] + 2048 + lds_off);
      async16(w2bf + gB0 + k0, Bs[nb] + lds_off);
      async16(w2bf + gB1 + k0, Bs[nb] + 2048 + lds_off);
    }
    bf16x8 af[4], bfv[4];
#pragma unroll
    for (int i = 0; i < 4; i++)
      af[i] = *(const bf16x8*)(As[cur] + (wm + i * 16 + l15) * 32 + quad * 8);
#pragma unroll
    for (int j = 0; j < 4; j++)
      bfv[j] = *(const bf16x8*)(Bs[cur] + (wn + j * 16 + l15) * 32 + quad * 8);
#pragma unroll
    for (int i = 0; i < 4; i++)
#pragma unroll
      for (int j = 0; j < 4; j++)
        acc[i][j] = __builtin_amdgcn_mfma_f32_16x16x32_bf16(af[i], bfv[j], acc[i][j], 0, 0, 0);
    cur = (cur == 2) ? 0 : cur + 1;
  }

  // epilogue: gated atomic scatter into out (replaces ybuf + combine kernel)
#pragma unroll
  for (int i = 0; i < 4; i++)
#pragma unroll
    for (int r = 0; r < 4; r++) {
      const int ml = wm + i * 16 + quad * 4 + r;
      const int m = m0 + ml;
      if (m < cnt) {
        const int t = tok[ml];
        const float g = gt[ml];
        float* orow = out + (size_t)t * Dm + n0;
#pragma unroll
        for (int j = 0; j < 4; j++) {
          const int n = wn + j * 16 + l15;
          float v = acc[i][j][r];
          if (ks == 0) v += b2[(size_t)e * Dm + n0 + n];
          atomicAdd(orow + n, g * v);
        }
      }
    }
}

extern "C" void kernel_launch(void* const* d_in, const int* in_sizes, int n_in,
                              void* d_out, int out_size, void* d_ws, size_t ws_size,
                              hipStream_t stream) {
  const float* x     = (const float*)d_in[0];
  const float* noise = (const float*)d_in[1];
  const float* Wr    = (const float*)d_in[2];
  const float* br    = (const float*)d_in[3];
  const float* Wn    = (const float*)d_in[4];
  const float* bn    = (const float*)d_in[5];
  const float* W1    = (const float*)d_in[6];
  const float* b1    = (const float*)d_in[7];
  const float* W2    = (const float*)d_in[8];
  const float* b2    = (const float*)d_in[9];

  float* out        = (float*)d_out;
  float* out_gating = out + (size_t)T_TOK * Dm;

  // ws layout (~200 MB total)
  char* ws = (char*)d_ws;
  unsigned short* w1bf = (unsigned short*)(ws);                 //  64 MiB [E][H][D] bf16
  unsigned short* w2bf = (unsigned short*)(ws + 67108864);      //  64 MiB [E][D][H] bf16
  unsigned short* xbf  = (unsigned short*)(ws + 134217728);     //   8 MiB [T][D] bf16
  unsigned short* hbuf = (unsigned short*)(ws + 142606336);     //  64 MiB [2T][H] bf16
  int*   lists         = (int*)(ws + 209715200);                // 128 KiB [E][T]
  float* gslot         = (float*)(ws + 209846272);              // 128 KiB [E][T]
  int*   counts        = (int*)(ws + 209977344);                //  32 B   [E]

  hipMemsetAsync(counts, 0, Em * sizeof(int), stream);
  hipMemsetAsync(out, 0, (size_t)T_TOK * Dm * sizeof(float), stream);  // atomic-accum target

  // weights -> bf16 transposed (k-contiguous for MFMA B operand), 128x32 vectorized tiles
  transpose_cvt_kernel<<<dim3(Hm / 32, Dm / 128, Em), 256, 0, stream>>>(W1, w1bf, Dm, Hm);
  transpose_cvt_kernel<<<dim3(Dm / 32, Hm / 128, Em), 256, 0, stream>>>(W2, w2bf, Hm, Dm);

  router_kernel<<<T_TOK / 4, 256, 0, stream>>>(x, noise, Wr, br, Wn, bn,
                                               out_gating, lists, counts, gslot, xbf);

  // expert in blockIdx.x => linear_id % 8 == expert => per-expert XCD affinity (T1)
  gemm1_kernel<<<dim3(Em, 16, Hm / 128), 256, 0, stream>>>(xbf, w1bf, b1, counts, lists, hbuf);
  gemm2_kernel<<<dim3(Em, 16, (Dm / 128) * KSPLIT), 256, 0, stream>>>(hbuf, w2bf, counts, lists,
                                                                      gslot, b2, out);
}

// Round 4
// 735.714 us; speedup vs baseline: 1.0248x; 1.0248x over previous
//
#include <hip/hip_runtime.h>
#include <stdint.h>

// Problem constants (B=2, S=2048 -> T=4096 tokens)
#define T_TOK 4096
#define Dm    1024
#define Em    8
#define Hm    4096
#define NSLOT (2 * T_TOK)   // 8192 (token,expert) slots

typedef __bf16 bf16x8 __attribute__((ext_vector_type(8)));
typedef float  f32x4  __attribute__((ext_vector_type(4)));
typedef unsigned short us8v __attribute__((ext_vector_type(8)));

__device__ __forceinline__ unsigned short f2bf(float f) {
  union { float f; unsigned int u; } c; c.f = f;
  unsigned int u = c.u;
  unsigned int r = u + 0x7fffu + ((u >> 16) & 1u);  // round-to-nearest-even
  return (unsigned short)(r >> 16);
}

// async 16B/lane global->LDS copy (wave-uniform LDS base + lane*16)
__device__ __forceinline__ void async16(const void* g, void* l) {
  __builtin_amdgcn_global_load_lds(
      (const __attribute__((address_space(1))) void*)g,
      (__attribute__((address_space(3))) void*)l, 16, 0, 0);
}

// ---------------- transpose + fp32->bf16 convert (128R x 32C tiles) ----------------
// src: [E][R][C] fp32, dst: [E][C][R] bf16.  grid (C/32, R/128, E), block 256.
__global__ __launch_bounds__(256) void transpose_cvt_kernel(
    const float* __restrict__ src, unsigned short* __restrict__ dst, int R, int C) {
  __shared__ float tile[128][33];
  const int e = blockIdx.z;
  const float* s = src + (size_t)e * R * C;
  unsigned short* d = dst + (size_t)e * R * C;
  const int c0 = blockIdx.x * 32, r0 = blockIdx.y * 128;
  const int tid = threadIdx.x;

  const int lrow = tid >> 3, lc = (tid & 7) * 4;
#pragma unroll
  for (int p = 0; p < 4; ++p) {
    const int row = lrow + p * 32;
    float4 v = *(const float4*)(s + (size_t)(r0 + row) * C + c0 + lc);
    tile[row][lc + 0] = v.x; tile[row][lc + 1] = v.y;
    tile[row][lc + 2] = v.z; tile[row][lc + 3] = v.w;
  }
  __syncthreads();

  const int rb = (tid & 15) * 8;
#pragma unroll
  for (int p = 0; p < 2; ++p) {
    const int c = (tid >> 4) + p * 16;
    us8v o;
#pragma unroll
    for (int k = 0; k < 8; ++k) o[k] = f2bf(tile[rb + k][c]);
    *(us8v*)(d + (size_t)(c0 + c) * R + r0 + rb) = o;
  }
}

// ---------------- router: one wave per token (also emits xbf = bf16(x)) ----------------
__global__ __launch_bounds__(256) void router_kernel(
    const float* __restrict__ x, const float* __restrict__ noise,
    const float* __restrict__ Wr, const float* __restrict__ br,
    const float* __restrict__ Wn, const float* __restrict__ bn,
    float* __restrict__ out_gating, int* __restrict__ lists,
    int* __restrict__ counts, int* __restrict__ expt,
    int* __restrict__ pos, float* __restrict__ gsel,
    unsigned short* __restrict__ xbf) {
  const int wave = threadIdx.x >> 6, lane = threadIdx.x & 63;
  const int t = blockIdx.x * 4 + wave;
  const float* xt = x + (size_t)t * Dm;
  float accR[Em] = {}, accN[Em] = {};
  for (int d = lane; d < Dm; d += 64) {
    const float xv = xt[d];
    xbf[(size_t)t * Dm + d] = f2bf(xv);       // fused x -> bf16 cast
    const float* wr = Wr + d * Em;
    const float* wn = Wn + d * Em;
#pragma unroll
    for (int e = 0; e < Em; e++) { accR[e] += xv * wr[e]; accN[e] += xv * wn[e]; }
  }
#pragma unroll
  for (int e = 0; e < Em; e++)
    for (int off = 32; off > 0; off >>= 1) {
      accR[e] += __shfl_down(accR[e], off, 64);
      accN[e] += __shfl_down(accN[e], off, 64);
    }
  if (lane == 0) {
    float lg[Em], ny[Em];
#pragma unroll
    for (int e = 0; e < Em; e++) {
      lg[e] = accR[e] + br[e];
      float nl = accN[e] + bn[e];
      float sp = fmaxf(nl, 0.f) + log1pf(expf(-fabsf(nl)));  // stable softplus
      ny[e] = lg[e] + noise[(size_t)t * Em + e] * sp;
    }
    // top-2, first-occurrence tie-break (matches lax.top_k)
    int i0 = 0;
#pragma unroll
    for (int e = 1; e < Em; e++) if (ny[e] > ny[i0]) i0 = e;
    int i1 = (i0 == 0) ? 1 : 0;
#pragma unroll
    for (int e = 0; e < Em; e++) if (e != i0 && ny[e] > ny[i1]) i1 = e;
    const float e1 = expf(ny[i1] - ny[i0]);
    const float g0 = 1.f / (1.f + e1), g1 = e1 / (1.f + e1);
    // dense softmax of clean logits (output 2)
    float m = lg[0];
#pragma unroll
    for (int e = 1; e < Em; e++) m = fmaxf(m, lg[e]);
    float s = 0.f;
#pragma unroll
    for (int e = 0; e < Em; e++) s += expf(lg[e] - m);
#pragma unroll
    for (int e = 0; e < Em; e++) out_gating[(size_t)t * Em + e] = expf(lg[e] - m) / s;
    // append to expert lists + inverse map
    int p0 = atomicAdd(&counts[i0], 1); lists[i0 * T_TOK + p0] = t;
    int p1 = atomicAdd(&counts[i1], 1); lists[i1 * T_TOK + p1] = t;
    expt[2 * t] = i0; expt[2 * t + 1] = i1;
    pos[2 * t] = p0;  pos[2 * t + 1] = p1;
    gsel[2 * t] = g0; gsel[2 * t + 1] = g1;
  }
}

// ---------------- GEMM1: hbuf[base+m][h] = relu(Xg[m] . W1t[h] + b1) ----------------
// BM=256 x BN=128, BK=32, 512 threads (8 waves, 4m x 2n of 64x64).
// 3-deep LDS pipeline, prefetch distance 2, counted vmcnt(3) + raw s_barrier.
// grid (E, 8 m-tiles, 32 n-tiles): expert = blockIdx.x = linear_id % 8 -> XCD affinity.
__global__ __launch_bounds__(512) void gemm1_kernel(
    const unsigned short* __restrict__ xbf, const unsigned short* __restrict__ w1bf,
    const float* __restrict__ b1, const int* __restrict__ counts,
    const int* __restrict__ lists, unsigned short* __restrict__ hbuf) {
  const int e = blockIdx.x;
  const int cnt = counts[e];
  const int m0 = blockIdx.y * 256;
  if (m0 >= cnt) return;
  const int n0 = blockIdx.z * 128;
  int base = 0;
  for (int i = 0; i < e; i++) base += counts[i];

  __shared__ __align__(16) unsigned short As[3][256 * 32];  // 16 KiB each
  __shared__ __align__(16) unsigned short Bs[3][128 * 32];  //  8 KiB each
  __shared__ int tok[256];

  const int tid = threadIdx.x;
  if (tid < 256) {
    int m = m0 + tid;
    tok[tid] = (m < cnt) ? lists[e * T_TOK + m] : 0;
  }
  __syncthreads();

  const int part = tid & 3;          // 16B chunk within 64B row
  const int rr = tid >> 2;           // rows 0..127
  const size_t gA0 = (size_t)tok[rr] * Dm + part * 8;
  const size_t gA1 = (size_t)tok[rr + 128] * Dm + part * 8;
  const size_t gB0 = ((size_t)e * Hm + n0 + rr) * Dm + part * 8;

  const int lane = tid & 63, wv = tid >> 6;
  const int quad = lane >> 4, l15 = lane & 15;
  const int wm = (wv >> 1) * 64, wn = (wv & 1) * 64;
  const int lds_off = wv * 512;      // wave-uniform base (lane*16B implicit)

  f32x4 acc[4][4] = {};

  // prologue: tiles 0 and 1 in flight (6 loads/wave)
  async16(xbf + gA0,       As[0] + lds_off);
  async16(xbf + gA1,       As[0] + 4096 + lds_off);
  async16(w1bf + gB0,      Bs[0] + lds_off);
  async16(xbf + gA0 + 32,  As[1] + lds_off);
  async16(xbf + gA1 + 32,  As[1] + 4096 + lds_off);
  async16(w1bf + gB0 + 32, Bs[1] + lds_off);

  const int NI = Dm / 32;  // 32
  int cur = 0;
  for (int it = 0; it < NI; ++it) {
    if (it < NI - 1) {
      asm volatile("s_waitcnt vmcnt(3)" ::: "memory");  // tile it landed (it+1's 3 remain)
    } else {
      asm volatile("s_waitcnt vmcnt(0)" ::: "memory");
    }
    __builtin_amdgcn_s_barrier();
    __builtin_amdgcn_sched_barrier(0);
    if (it + 2 < NI) {
      const int k0 = (it + 2) * 32;
      int nb = cur + 2; if (nb >= 3) nb -= 3;
      async16(xbf + gA0 + k0, As[nb] + lds_off);
      async16(xbf + gA1 + k0, As[nb] + 4096 + lds_off);
      async16(w1bf + gB0 + k0, Bs[nb] + lds_off);
    }
    bf16x8 af[4], bfv[4];
#pragma unroll
    for (int i = 0; i < 4; i++)
      af[i] = *(const bf16x8*)(As[cur] + (wm + i * 16 + l15) * 32 + quad * 8);
#pragma unroll
    for (int j = 0; j < 4; j++)
      bfv[j] = *(const bf16x8*)(Bs[cur] + (wn + j * 16 + l15) * 32 + quad * 8);
#pragma unroll
    for (int i = 0; i < 4; i++)
#pragma unroll
      for (int j = 0; j < 4; j++)
        acc[i][j] = __builtin_amdgcn_mfma_f32_16x16x32_bf16(af[i], bfv[j], acc[i][j], 0, 0, 0);
    cur = (cur == 2) ? 0 : cur + 1;
  }

#pragma unroll
  for (int i = 0; i < 4; i++)
#pragma unroll
    for (int r = 0; r < 4; r++) {
      const int ml = wm + i * 16 + quad * 4 + r;   // 0..255
      const int m = m0 + ml;
      if (m < cnt) {
#pragma unroll
        for (int j = 0; j < 4; j++) {
          const int n = n0 + wn + j * 16 + l15;
          float v = acc[i][j][r] + b1[(size_t)e * Hm + n];
          v = fmaxf(v, 0.f);
          hbuf[(size_t)(base + m) * Hm + n] = f2bf(v);
        }
      }
    }
}

// ---------------- GEMM2: ybuf[base+m][d] = H[base+m] . W2t[d] (full K, no split) ----------------
// BM=256 x BN=128, same 3-deep counted-vmcnt pipeline; grid (E, 8 m, 8 n).
__global__ __launch_bounds__(512) void gemm2_kernel(
    const unsigned short* __restrict__ hbuf, const unsigned short* __restrict__ w2bf,
    const int* __restrict__ counts, float* __restrict__ ybuf) {
  const int e = blockIdx.x;
  const int cnt = counts[e];
  const int m0 = blockIdx.y * 256;
  if (m0 >= cnt) return;
  const int n0 = blockIdx.z * 128;   // N = 1024
  int base = 0;
  for (int i = 0; i < e; i++) base += counts[i];

  __shared__ __align__(16) unsigned short As[3][256 * 32];
  __shared__ __align__(16) unsigned short Bs[3][128 * 32];

  const int tid = threadIdx.x;
  const int part = tid & 3;
  const int rr = tid >> 2;           // 0..127
  const int rowA0 = min(base + m0 + rr, NSLOT - 1);        // clamp: tail rows junk, unused
  const int rowA1 = min(base + m0 + rr + 128, NSLOT - 1);
  const size_t gA0 = (size_t)rowA0 * Hm + part * 8;
  const size_t gA1 = (size_t)rowA1 * Hm + part * 8;
  const size_t gB0 = ((size_t)e * Dm + n0 + rr) * Hm + part * 8;

  const int lane = tid & 63, wv = tid >> 6;
  const int quad = lane >> 4, l15 = lane & 15;
  const int wm = (wv >> 1) * 64, wn = (wv & 1) * 64;
  const int lds_off = wv * 512;

  f32x4 acc[4][4] = {};

  async16(hbuf + gA0,       As[0] + lds_off);
  async16(hbuf + gA1,       As[0] + 4096 + lds_off);
  async16(w2bf + gB0,       Bs[0] + lds_off);
  async16(hbuf + gA0 + 32,  As[1] + lds_off);
  async16(hbuf + gA1 + 32,  As[1] + 4096 + lds_off);
  async16(w2bf + gB0 + 32,  Bs[1] + lds_off);

  const int NI = Hm / 32;  // 128
  int cur = 0;
  for (int it = 0; it < NI; ++it) {
    if (it < NI - 1) {
      asm volatile("s_waitcnt vmcnt(3)" ::: "memory");
    } else {
      asm volatile("s_waitcnt vmcnt(0)" ::: "memory");
    }
    __builtin_amdgcn_s_barrier();
    __builtin_amdgcn_sched_barrier(0);
    if (it + 2 < NI) {
      const int k0 = (it + 2) * 32;
      int nb = cur + 2; if (nb >= 3) nb -= 3;
      async16(hbuf + gA0 + k0, As[nb] + lds_off);
      async16(hbuf + gA1 + k0, As[nb] + 4096 + lds_off);
      async16(w2bf + gB0 + k0, Bs[nb] + lds_off);
    }
    bf16x8 af[4], bfv[4];
#pragma unroll
    for (int i = 0; i < 4; i++)
      af[i] = *(const bf16x8*)(As[cur] + (wm + i * 16 + l15) * 32 + quad * 8);
#pragma unroll
    for (int j = 0; j < 4; j++)
      bfv[j] = *(const bf16x8*)(Bs[cur] + (wn + j * 16 + l15) * 32 + quad * 8);
#pragma unroll
    for (int i = 0; i < 4; i++)
#pragma unroll
      for (int j = 0; j < 4; j++)
        acc[i][j] = __builtin_amdgcn_mfma_f32_16x16x32_bf16(af[i], bfv[j], acc[i][j], 0, 0, 0);
    cur = (cur == 2) ? 0 : cur + 1;
  }

#pragma unroll
  for (int i = 0; i < 4; i++)
#pragma unroll
    for (int r = 0; r < 4; r++) {
      const int ml = wm + i * 16 + quad * 4 + r;
      const int m = m0 + ml;
      if (m < cnt) {
#pragma unroll
        for (int j = 0; j < 4; j++) {
          const int n = n0 + wn + j * 16 + l15;
          ybuf[(size_t)(base + m) * Dm + n] = acc[i][j][r];
        }
      }
    }
}

// ---------------- combine: out[t] = sum_k g_k * (ybuf[slot_k] + b2[e_k]) ----------------
__global__ __launch_bounds__(256) void combine_kernel(
    const float* __restrict__ ybuf, const float* __restrict__ b2,
    const int* __restrict__ counts, const int* __restrict__ expt,
    const int* __restrict__ pos, const float* __restrict__ gsel,
    float* __restrict__ out) {
  const int t = blockIdx.x;
  const int e0 = expt[2 * t], e1 = expt[2 * t + 1];
  const float g0 = gsel[2 * t], g1 = gsel[2 * t + 1];
  int b0 = 0, b1 = 0;
  for (int i = 0; i < e0; i++) b0 += counts[i];
  for (int i = 0; i < e1; i++) b1 += counts[i];
  const size_t s0 = (size_t)(b0 + pos[2 * t]) * Dm;
  const size_t s1 = (size_t)(b1 + pos[2 * t + 1]) * Dm;
  const int c = threadIdx.x * 4;
  float4 y0 = *(const float4*)(ybuf + s0 + c);
  float4 y1 = *(const float4*)(ybuf + s1 + c);
  float4 z0 = *(const float4*)(b2 + (size_t)e0 * Dm + c);
  float4 z1 = *(const float4*)(b2 + (size_t)e1 * Dm + c);
  float4 o;
  o.x = g0 * (y0.x + z0.x) + g1 * (y1.x + z1.x);
  o.y = g0 * (y0.y + z0.y) + g1 * (y1.y + z1.y);
  o.z = g0 * (y0.z + z0.z) + g1 * (y1.z + z1.z);
  o.w = g0 * (y0.w + z0.w) + g1 * (y1.w + z1.w);
  *(float4*)(out + (size_t)t * Dm + c) = o;
}

extern "C" void kernel_launch(void* const* d_in, const int* in_sizes, int n_in,
                              void* d_out, int out_size, void* d_ws, size_t ws_size,
                              hipStream_t stream) {
  const float* x     = (const float*)d_in[0];
  const float* noise = (const float*)d_in[1];
  const float* Wr    = (const float*)d_in[2];
  const float* br    = (const float*)d_in[3];
  const float* Wn    = (const float*)d_in[4];
  const float* bn    = (const float*)d_in[5];
  const float* W1    = (const float*)d_in[6];
  const float* b1    = (const float*)d_in[7];
  const float* W2    = (const float*)d_in[8];
  const float* b2    = (const float*)d_in[9];

  float* out        = (float*)d_out;
  float* out_gating = out + (size_t)T_TOK * Dm;

  // ws layout (~200 MB total)
  char* ws = (char*)d_ws;
  unsigned short* w1bf = (unsigned short*)(ws);                 //  64 MiB [E][H][D] bf16
  unsigned short* w2bf = (unsigned short*)(ws + 67108864);      //  64 MiB [E][D][H] bf16
  unsigned short* xbf  = (unsigned short*)(ws + 134217728);     //   8 MiB [T][D] bf16
  unsigned short* hbuf = (unsigned short*)(ws + 142606336);     //  64 MiB [2T][H] bf16
  float* ybuf          = (float*)(ws);                          //  32 MiB [2T][D] fp32, aliases w1bf (dead after gemm1)
  int*   lists         = (int*)(ws + 209715200);                // 128 KiB [E][T]
  int*   expt          = (int*)(ws + 209846272);                //  32 KiB [T][2]
  int*   pos           = (int*)(ws + 209879040);                //  32 KiB [T][2]
  float* gsel          = (float*)(ws + 209911808);              //  32 KiB [T][2]
  int*   counts        = (int*)(ws + 209944576);                //  32 B   [E]

  hipMemsetAsync(counts, 0, Em * sizeof(int), stream);

  // weights -> bf16 transposed (k-contiguous for MFMA B operand)
  transpose_cvt_kernel<<<dim3(Hm / 32, Dm / 128, Em), 256, 0, stream>>>(W1, w1bf, Dm, Hm);
  transpose_cvt_kernel<<<dim3(Dm / 32, Hm / 128, Em), 256, 0, stream>>>(W2, w2bf, Hm, Dm);

  router_kernel<<<T_TOK / 4, 256, 0, stream>>>(x, noise, Wr, br, Wn, bn,
                                               out_gating, lists, counts, expt, pos, gsel, xbf);

  // expert in blockIdx.x => linear_id % 8 == expert => per-expert XCD affinity (T1)
  gemm1_kernel<<<dim3(Em, 8, Hm / 128), 512, 0, stream>>>(xbf, w1bf, b1, counts, lists, hbuf);
  gemm2_kernel<<<dim3(Em, 8, Dm / 128), 512, 0, stream>>>(hbuf, w2bf, counts, ybuf);
  combine_kernel<<<T_TOK, 256, 0, stream>>>(ybuf, b2, counts, expt, pos, gsel, out);
}